// Round 9
// baseline (143.356 us; speedup 1.0000x reference)
//
#include <hip/hip_runtime.h>
#include <math.h>

// local_mixer via bf16 MFMA, swapped-QK^T, in-register softmax + permlane PV.
// R9 = R8 with the sum-exchange bug fixed: the permlane32_swap on two copies
// of the SAME value let the regalloc coalesce them into one register (swap
// became a self-swap -> tot = 2*other_half). Replaced by __shfl_xor(sum,32),
// the reduction validated in R5. Everything else identical to R8:
// pre-PV normalize (inv folded into cvt_pk), no ones-column, setprio on MFMA.
//   x:[8,256,256,64]f32  W:[192,64]f32  b:[192]f32  pos:[1,8,64,64]f32
//   out:[8192,64,64]f32

typedef __attribute__((ext_vector_type(8)))  short bf16x8;
typedef __attribute__((ext_vector_type(4)))  float f32x4;
typedef __attribute__((ext_vector_type(16))) float f32x16;

__device__ inline unsigned int cvt_pk_bf16(float lo, float hi) {
    unsigned int r;
    asm("v_cvt_pk_bf16_f32 %0, %1, %2" : "=v"(r) : "v"(lo), "v"(hi));
    return r;
}
__device__ inline void permswap(unsigned int &a, unsigned int &b) {
    asm("v_permlane32_swap_b32 %0, %1" : "+v"(a), "+v"(b));
}
__device__ inline bf16x8 pack8(float4 a, float4 b) {
    union { unsigned int u[4]; bf16x8 v; } r;
    r.u[0] = cvt_pk_bf16(a.x, a.y);
    r.u[1] = cvt_pk_bf16(a.z, a.w);
    r.u[2] = cvt_pk_bf16(b.x, b.y);
    r.u[3] = cvt_pk_bf16(b.z, b.w);
    return r.v;
}

// ---- prep: pos -> f32 S^T-C-layout fragments, *log2e, into d_ws (128 KB) ----
// flat = (((h*2 + it)*2 + jt)*64 + lane)*16 + reg
__global__ __launch_bounds__(256) void prep_pos(const float* __restrict__ pos,
                                                float* __restrict__ pp)
{
    int flat = blockIdx.x * 256 + threadIdx.x;   // 0..32767
    int r  = flat & 15;
    int ln = (flat >> 4) & 63;
    int jt = (flat >> 10) & 1;
    int it = (flat >> 11) & 1;
    int h  = flat >> 12;
    int j = jt*32 + (r & 3) + 8*(r >> 2) + 4*(ln >> 5);   // S^T row
    int i = it*32 + (ln & 31);                            // S^T col
    pp[flat] = pos[(h*64 + i)*64 + j] * 1.4426950408889634f;
}

__global__ __launch_bounds__(256, 3) void lm_mfma(const float* __restrict__ x,
                                                  const float* __restrict__ Wq,
                                                  const float* __restrict__ bq,
                                                  const float* __restrict__ ppf,
                                                  float* __restrict__ out)
{
    // 32 KB LDS. Chunk-swizzle: 8-bf16 chunk c8 of row r at c8^(r&7).
    __shared__ unsigned short sX [64*64];  // x window [n][c]
    __shared__ unsigned short sQ [64*64];  // q (scaled*log2e) [i][d]
    __shared__ unsigned short sK [64*64];  // k [j][d]
    __shared__ unsigned short sVT[64*64];  // v^T [c][j]

    const int tid = threadIdx.x;
    const int w   = blockIdx.x;
    const int ln  = tid & 63;
    const int wv  = tid >> 6;
    const int lr  = ln & 15;
    const int lg  = ln >> 4;

    const int bi = w >> 10, mm = w & 1023;
    const int mh = mm >> 5, mw = mm & 31;
    const float* xwin = x + ((size_t)(bi*256 + mh*8)*256 + mw*8)*64;

    // ---- stage x -> sX (bf16, swizzled) ----
    #pragma unroll
    for (int r = 0; r < 4; ++r) {
        const int f4 = tid + r*256;
        const int n  = f4 >> 4;
        const int c  = (f4 & 15) * 4;
        const float4 v = *(const float4*)(xwin + ((size_t)(n>>3)*256 + (n&7))*64 + c);
        uint2 u;
        u.x = cvt_pk_bf16(v.x, v.y);
        u.y = cvt_pk_bf16(v.z, v.w);
        *(uint2*)&sX[n*64 + (((c>>3) ^ (n&7))<<3) + (c&7)] = u;
    }

    // ---- W fragments: wave wv owns d-tiles {wv, wv+4, wv+8} ----
    bf16x8 wfrag[3][2];
    #pragma unroll
    for (int t = 0; t < 3; ++t) {
        const int d = (wv + 4*t)*16 + lr;
        #pragma unroll
        for (int kt = 0; kt < 2; ++kt) {
            const float* base = Wq + (size_t)d*64 + kt*32 + lg*8;
            wfrag[t][kt] = pack8(*(const float4*)base, *(const float4*)(base+4));
        }
    }
    const float qs = 0.35355339059327373f * 1.4426950408889634f;  // 8^-0.5 * log2e
    const float4 bqQr = *(const float4*)(bq       + wv*16 + lg*4);
    const float4 bqK  = *(const float4*)(bq + 64  + wv*16 + lg*4);
    const float  bqV  = bq[128 + wv*16 + lr];
    float4 bqQs;
    bqQs.x = bqQr.x*qs; bqQs.y = bqQr.y*qs; bqQs.z = bqQr.z*qs; bqQs.w = bqQr.w*qs;

    __syncthreads();

    // ---- QKV MFMAs (16x16x32) ----
    f32x4 aQ[4], aK[4], aV[4];
    #pragma unroll
    for (int nt = 0; nt < 4; ++nt) { aQ[nt]=0; aK[nt]=0; aV[nt]=0; }

    __builtin_amdgcn_s_setprio(1);
    #pragma unroll
    for (int nt = 0; nt < 4; ++nt) {
        #pragma unroll
        for (int kt = 0; kt < 2; ++kt) {
            const int n  = lr + nt*16;
            const int c8 = lg + kt*4;
            const bf16x8 xf = *(const bf16x8*)&sX[n*64 + ((c8 ^ (n&7))<<3)];
            aQ[nt] = __builtin_amdgcn_mfma_f32_16x16x32_bf16(wfrag[0][kt], xf, aQ[nt], 0,0,0);
            aK[nt] = __builtin_amdgcn_mfma_f32_16x16x32_bf16(wfrag[1][kt], xf, aK[nt], 0,0,0);
            aV[nt] = __builtin_amdgcn_mfma_f32_16x16x32_bf16(xf, wfrag[2][kt], aV[nt], 0,0,0);
        }
    }
    __builtin_amdgcn_s_setprio(0);

    #pragma unroll
    for (int nt = 0; nt < 4; ++nt) {
        const int n  = lr + nt*16;
        const int d0 = wv*16 + lg*4;
        const int qidx = n*64 + (((d0>>3) ^ (n&7))<<3) + (d0&7);
        uint2 uq, uk;
        uq.x = cvt_pk_bf16(fmaf(aQ[nt][0], qs, bqQs.x), fmaf(aQ[nt][1], qs, bqQs.y));
        uq.y = cvt_pk_bf16(fmaf(aQ[nt][2], qs, bqQs.z), fmaf(aQ[nt][3], qs, bqQs.w));
        uk.x = cvt_pk_bf16(aK[nt][0]+bqK.x, aK[nt][1]+bqK.y);
        uk.y = cvt_pk_bf16(aK[nt][2]+bqK.z, aK[nt][3]+bqK.w);
        *(uint2*)&sQ[qidx] = uq;
        *(uint2*)&sK[qidx] = uk;
        const int cc = wv*16 + lr;
        const int n0 = nt*16 + lg*4;
        uint2 uv;
        uv.x = cvt_pk_bf16(aV[nt][0]+bqV, aV[nt][1]+bqV);
        uv.y = cvt_pk_bf16(aV[nt][2]+bqV, aV[nt][3]+bqV);
        *(uint2*)&sVT[cc*64 + (((n0>>3) ^ (cc&7))<<3) + (n0&7)] = uv;
    }

    __syncthreads();

    // ---- attention: wave wv -> heads {2wv, 2wv+1}; both i-tiles interleaved ----
    const int cB  = ln & 31;     // PV output column (channel within head; <8 valid)
    const int hiB = ln >> 5;

    #pragma unroll 1
    for (int hh = 0; hh < 2; ++hh) {
        const int h = wv*2 + hh;

        // PV B-frags (32x32x16): lane = col cB (<8 = head channels, else zero);
        // k = 8*hiB + {0..7} = j.
        bf16x8 vb[4];
        #pragma unroll
        for (int kt = 0; kt < 4; ++kt) {
            bf16x8 z = {};
            vb[kt] = z;
            if (cB < 8) {
                const int cc = h*8 + cB;
                const int ch = 2*kt + hiB;
                vb[kt] = *(const bf16x8*)&sVT[cc*64 + ((ch ^ (cc&7))<<3)];
            }
        }

        // C-init = pos fragments (f32, *log2e, pre-permuted), both i-tiles
        f32x16 C[2][2];
        #pragma unroll
        for (int it = 0; it < 2; ++it)
            #pragma unroll
            for (int jt = 0; jt < 2; ++jt)
                C[it][jt] = *(const f32x16*)(ppf + ((((h*2+it)*2 + jt)*64) + ln)*16);

        // swapped QK^T: S^T = K·Q^T (32x32x16, K=8 of 16). kf shared by both i-tiles.
        bf16x8 qf0 = {}, qf1 = {}, kf0 = {}, kf1 = {};
        if (ln < 32) {
            qf0 = *(const bf16x8*)&sQ[ln*64 + ((h ^ (ln&7))<<3)];
            const int i1 = 32 + ln;
            qf1 = *(const bf16x8*)&sQ[i1*64 + ((h ^ (i1&7))<<3)];
            kf0 = *(const bf16x8*)&sK[ln*64 + ((h ^ (ln&7))<<3)];
            kf1 = *(const bf16x8*)&sK[i1*64 + ((h ^ (i1&7))<<3)];
        }
        __builtin_amdgcn_s_setprio(1);
        C[0][0] = __builtin_amdgcn_mfma_f32_32x32x16_bf16(kf0, qf0, C[0][0], 0,0,0);
        C[0][1] = __builtin_amdgcn_mfma_f32_32x32x16_bf16(kf1, qf0, C[0][1], 0,0,0);
        C[1][0] = __builtin_amdgcn_mfma_f32_32x32x16_bf16(kf0, qf1, C[1][0], 0,0,0);
        C[1][1] = __builtin_amdgcn_mfma_f32_32x32x16_bf16(kf1, qf1, C[1][1], 0,0,0);
        __builtin_amdgcn_s_setprio(0);

        // exp2 in place (no max: scores bounded; validated R3-R7), then per-it
        // row sum: lane-local 31-add tree + cross-half shfl_xor(32) + rcp.
        float inv[2];
        #pragma unroll
        for (int it = 0; it < 2; ++it) {
            float t[8];
            #pragma unroll
            for (int jt = 0; jt < 2; ++jt)
                #pragma unroll
                for (int g = 0; g < 4; ++g) {
                    const int b = g*4;
                    C[it][jt][b+0] = __builtin_amdgcn_exp2f(C[it][jt][b+0]);
                    C[it][jt][b+1] = __builtin_amdgcn_exp2f(C[it][jt][b+1]);
                    C[it][jt][b+2] = __builtin_amdgcn_exp2f(C[it][jt][b+2]);
                    C[it][jt][b+3] = __builtin_amdgcn_exp2f(C[it][jt][b+3]);
                    t[jt*4+g] = (C[it][jt][b+0]+C[it][jt][b+1])
                              + (C[it][jt][b+2]+C[it][jt][b+3]);
                }
            const float sum = ((t[0]+t[1])+(t[2]+t[3])) + ((t[4]+t[5])+(t[6]+t[7]));
            // lanes l and l^32 hold the same query i with the two j-halves
            const float tot = sum + __shfl_xor(sum, 32, 64);
            inv[it] = __builtin_amdgcn_rcpf(tot);
        }

        // PV: A-frags built in-register (cvt_pk of normalized P + permlane32_swap)
        f32x16 O[2]; O[0] = (f32x16){}; O[1] = (f32x16){};
        __builtin_amdgcn_s_setprio(1);
        #pragma unroll
        for (int it = 0; it < 2; ++it) {
            const float iv = inv[it];
            #pragma unroll
            for (int kt = 0; kt < 4; ++kt) {
                const int jt = kt >> 1;
                const int q8 = (kt & 1) * 8;
                unsigned int A0 = cvt_pk_bf16(C[it][jt][q8+0]*iv, C[it][jt][q8+1]*iv);
                unsigned int A1 = cvt_pk_bf16(C[it][jt][q8+2]*iv, C[it][jt][q8+3]*iv);
                unsigned int B0 = cvt_pk_bf16(C[it][jt][q8+4]*iv, C[it][jt][q8+5]*iv);
                unsigned int B1 = cvt_pk_bf16(C[it][jt][q8+6]*iv, C[it][jt][q8+7]*iv);
                permswap(A0, B0);
                permswap(A1, B1);
                union { unsigned int u[4]; bf16x8 v; } af;
                af.u[0] = A0; af.u[1] = A1; af.u[2] = B0; af.u[3] = B1;
                O[it] = __builtin_amdgcn_mfma_f32_32x32x16_bf16(af.v, vb[kt], O[it], 0,0,0);
            }
        }
        __builtin_amdgcn_s_setprio(0);

        // store: lane holds col c=cB (<8), rows i = (r&3)+8(r>>2)+4*hiB
        if (cB < 8) {
            #pragma unroll
            for (int it = 0; it < 2; ++it) {
                float* ob = out + (size_t)w*4096 + (size_t)(it*32)*64 + h*8 + cB;
                #pragma unroll
                for (int r = 0; r < 16; ++r) {
                    const int iloc = (r&3) + 8*(r>>2) + 4*hiB;
                    ob[(size_t)iloc*64] = O[it][r];
                }
            }
        }
    }
}

extern "C" void kernel_launch(void* const* d_in, const int* in_sizes, int n_in,
                              void* d_out, int out_size, void* d_ws, size_t ws_size,
                              hipStream_t stream)
{
    const float* x   = (const float*)d_in[0];
    const float* Wq  = (const float*)d_in[1];
    const float* bq  = (const float*)d_in[2];
    const float* pos = (const float*)d_in[3];
    float* out = (float*)d_out;
    float* pp  = (float*)d_ws;   // 128 KB

    hipLaunchKernelGGL(prep_pos, dim3(128), dim3(256), 0, stream, pos, pp);
    hipLaunchKernelGGL(lm_mfma, dim3(8192), dim3(256), 0, stream, x, Wq, bq, pp, out);
}

// Round 10
// 136.985 us; speedup vs baseline: 1.0465x; 1.0465x over previous
//
#include <hip/hip_runtime.h>
#include <math.h>

// local_mixer via bf16 MFMA, swapped-QK^T, in-register softmax + permlane PV.
// R10: occupancy-targeted rebuild of R5. LDS 24 KB (sVT aliases dead sX; V
// carried in AGPRs across a barrier). QKV in two passes (Q+K, then V) to cut
// peak registers. Attention unit-serial (min regs), no setprio.
//   x:[8,256,256,64]f32  W:[192,64]f32  b:[192]f32  pos:[1,8,64,64]f32
//   out:[8192,64,64]f32

typedef __attribute__((ext_vector_type(8)))  short bf16x8;
typedef __attribute__((ext_vector_type(4)))  float f32x4;
typedef __attribute__((ext_vector_type(16))) float f32x16;

__device__ inline unsigned int cvt_pk_bf16(float lo, float hi) {
    unsigned int r;
    asm("v_cvt_pk_bf16_f32 %0, %1, %2" : "=v"(r) : "v"(lo), "v"(hi));
    return r;
}
__device__ inline void permswap(unsigned int &a, unsigned int &b) {
    asm("v_permlane32_swap_b32 %0, %1" : "+v"(a), "+v"(b));
}
__device__ inline bf16x8 pack8(float4 a, float4 b) {
    union { unsigned int u[4]; bf16x8 v; } r;
    r.u[0] = cvt_pk_bf16(a.x, a.y);
    r.u[1] = cvt_pk_bf16(a.z, a.w);
    r.u[2] = cvt_pk_bf16(b.x, b.y);
    r.u[3] = cvt_pk_bf16(b.z, b.w);
    return r.v;
}

// ---- prep: pos -> f32 S^T-C-layout fragments, *log2e, into d_ws (128 KB) ----
// flat = (((h*2 + it)*2 + jt)*64 + lane)*16 + reg
__global__ __launch_bounds__(256) void prep_pos(const float* __restrict__ pos,
                                                float* __restrict__ pp)
{
    int flat = blockIdx.x * 256 + threadIdx.x;   // 0..32767
    int r  = flat & 15;
    int ln = (flat >> 4) & 63;
    int jt = (flat >> 10) & 1;
    int it = (flat >> 11) & 1;
    int h  = flat >> 12;
    int j = jt*32 + (r & 3) + 8*(r >> 2) + 4*(ln >> 5);   // S^T row
    int i = it*32 + (ln & 31);                            // S^T col
    pp[flat] = pos[(h*64 + i)*64 + j] * 1.4426950408889634f;
}

__global__ __launch_bounds__(256, 5) void lm_mfma(const float* __restrict__ x,
                                                  const float* __restrict__ Wq,
                                                  const float* __restrict__ bq,
                                                  const float* __restrict__ ppf,
                                                  float* __restrict__ out)
{
    // 24 KB LDS (6 blocks/CU by LDS). Chunk-swizzle: chunk c8 of row r at c8^(r&7).
    __shared__ unsigned short sXV[64*64];  // x window [n][c] during QKV; v^T [c][j] in attn
    __shared__ unsigned short sQ [64*64];  // q (scaled*log2e) [i][d]
    __shared__ unsigned short sK [64*64];  // k [j][d]

    const int tid = threadIdx.x;
    const int w   = blockIdx.x;
    const int ln  = tid & 63;
    const int wv  = tid >> 6;
    const int lr  = ln & 15;
    const int lg  = ln >> 4;

    const int bi = w >> 10, mm = w & 1023;
    const int mh = mm >> 5, mw = mm & 31;
    const float* xwin = x + ((size_t)(bi*256 + mh*8)*256 + mw*8)*64;

    // ---- stage x -> sXV (bf16, swizzled) ----
    #pragma unroll
    for (int r = 0; r < 4; ++r) {
        const int f4 = tid + r*256;
        const int n  = f4 >> 4;
        const int c  = (f4 & 15) * 4;
        const float4 v = *(const float4*)(xwin + ((size_t)(n>>3)*256 + (n&7))*64 + c);
        uint2 u;
        u.x = cvt_pk_bf16(v.x, v.y);
        u.y = cvt_pk_bf16(v.z, v.w);
        *(uint2*)&sXV[n*64 + (((c>>3) ^ (n&7))<<3) + (c&7)] = u;
    }

    const float qs = 0.35355339059327373f * 1.4426950408889634f;  // 8^-0.5 * log2e

    __syncthreads();

    // ---- QKV pass A: Q and K (wave wv owns d-tiles wv (Q), wv+4 (K)) ----
    {
        bf16x8 wfQ[2], wfK[2];
        #pragma unroll
        for (int kt = 0; kt < 2; ++kt) {
            const float* bz = Wq + (size_t)(wv*16 + lr)*64 + kt*32 + lg*8;
            wfQ[kt] = pack8(*(const float4*)bz, *(const float4*)(bz+4));
            bz += (size_t)64*64;
            wfK[kt] = pack8(*(const float4*)bz, *(const float4*)(bz+4));
        }
        const float4 bqQr = *(const float4*)(bq      + wv*16 + lg*4);
        const float4 bqK  = *(const float4*)(bq + 64 + wv*16 + lg*4);
        float4 bqQs;
        bqQs.x = bqQr.x*qs; bqQs.y = bqQr.y*qs; bqQs.z = bqQr.z*qs; bqQs.w = bqQr.w*qs;

        f32x4 aQ[4], aK[4];
        #pragma unroll
        for (int nt = 0; nt < 4; ++nt) { aQ[nt]=0; aK[nt]=0; }
        #pragma unroll
        for (int nt = 0; nt < 4; ++nt) {
            #pragma unroll
            for (int kt = 0; kt < 2; ++kt) {
                const int n  = lr + nt*16;
                const int c8 = lg + kt*4;
                const bf16x8 xf = *(const bf16x8*)&sXV[n*64 + ((c8 ^ (n&7))<<3)];
                aQ[nt] = __builtin_amdgcn_mfma_f32_16x16x32_bf16(wfQ[kt], xf, aQ[nt], 0,0,0);
                aK[nt] = __builtin_amdgcn_mfma_f32_16x16x32_bf16(wfK[kt], xf, aK[nt], 0,0,0);
            }
        }
        #pragma unroll
        for (int nt = 0; nt < 4; ++nt) {
            const int n  = lr + nt*16;
            const int d0 = wv*16 + lg*4;
            const int qidx = n*64 + (((d0>>3) ^ (n&7))<<3) + (d0&7);
            uint2 uq, uk;
            uq.x = cvt_pk_bf16(fmaf(aQ[nt][0], qs, bqQs.x), fmaf(aQ[nt][1], qs, bqQs.y));
            uq.y = cvt_pk_bf16(fmaf(aQ[nt][2], qs, bqQs.z), fmaf(aQ[nt][3], qs, bqQs.w));
            uk.x = cvt_pk_bf16(aK[nt][0]+bqK.x, aK[nt][1]+bqK.y);
            uk.y = cvt_pk_bf16(aK[nt][2]+bqK.z, aK[nt][3]+bqK.w);
            *(uint2*)&sQ[qidx] = uq;
            *(uint2*)&sK[qidx] = uk;
        }
    }

    // ---- QKV pass B: V into AGPRs (write deferred until sX is dead) ----
    f32x4 aV[4];
    {
        bf16x8 wfV[2];
        #pragma unroll
        for (int kt = 0; kt < 2; ++kt) {
            const float* bz = Wq + (size_t)(128 + wv*16 + lr)*64 + kt*32 + lg*8;
            wfV[kt] = pack8(*(const float4*)bz, *(const float4*)(bz+4));
        }
        #pragma unroll
        for (int nt = 0; nt < 4; ++nt) aV[nt] = 0;
        #pragma unroll
        for (int nt = 0; nt < 4; ++nt) {
            #pragma unroll
            for (int kt = 0; kt < 2; ++kt) {
                const int n  = lr + nt*16;
                const int c8 = lg + kt*4;
                const bf16x8 xf = *(const bf16x8*)&sXV[n*64 + ((c8 ^ (n&7))<<3)];
                aV[nt] = __builtin_amdgcn_mfma_f32_16x16x32_bf16(xf, wfV[kt], aV[nt], 0,0,0);
            }
        }
    }

    __syncthreads();   // everyone done reading sX

    {
        const float bqV = bq[128 + wv*16 + lr];
        #pragma unroll
        for (int nt = 0; nt < 4; ++nt) {
            const int cc = wv*16 + lr;
            const int n0 = nt*16 + lg*4;
            uint2 uv;
            uv.x = cvt_pk_bf16(aV[nt][0]+bqV, aV[nt][1]+bqV);
            uv.y = cvt_pk_bf16(aV[nt][2]+bqV, aV[nt][3]+bqV);
            *(uint2*)&sXV[cc*64 + (((n0>>3) ^ (cc&7))<<3) + (n0&7)] = uv;  // v^T over sX
        }
    }

    __syncthreads();   // sVT visible

    // ---- attention: wave wv -> heads {2wv, 2wv+1} x i-tiles {0,1}, unit-serial ----
    const int cB  = ln & 31;     // PV output column (channel within head; <8 valid)
    const int hiB = ln >> 5;

    #pragma unroll 1
    for (int hh = 0; hh < 2; ++hh) {
        const int h = wv*2 + hh;

        // PV B-frags (32x32x16): lane = col cB (<8 = head channels, else zero);
        // k = 8*hiB + {0..7} = j.
        bf16x8 vb[4];
        #pragma unroll
        for (int kt = 0; kt < 4; ++kt) {
            bf16x8 z = {};
            vb[kt] = z;
            if (cB < 8) {
                const int cc = h*8 + cB;
                const int ch = 2*kt + hiB;
                vb[kt] = *(const bf16x8*)&sXV[cc*64 + ((ch ^ (cc&7))<<3)];
            }
        }

        #pragma unroll 1
        for (int it = 0; it < 2; ++it) {
            // C-init = pos fragments (f32, *log2e, pre-permuted): pure loads
            f32x16 C[2];
            #pragma unroll
            for (int jt = 0; jt < 2; ++jt)
                C[jt] = *(const f32x16*)(ppf + ((((h*2+it)*2 + jt)*64) + ln)*16);

            // swapped QK^T: S^T tiles = K · Q^T (32x32x16, K=8 of 16; hi lanes zero)
            bf16x8 qf = {}, kf0 = {}, kf1 = {};
            if (ln < 32) {
                const int i = it*32 + ln;
                qf  = *(const bf16x8*)&sQ[i*64 + ((h ^ (i&7))<<3)];
                kf0 = *(const bf16x8*)&sK[ln*64 + ((h ^ (ln&7))<<3)];
                const int j1 = 32 + ln;
                kf1 = *(const bf16x8*)&sK[j1*64 + ((h ^ (j1&7))<<3)];
            }
            C[0] = __builtin_amdgcn_mfma_f32_32x32x16_bf16(kf0, qf, C[0], 0,0,0);
            C[1] = __builtin_amdgcn_mfma_f32_32x32x16_bf16(kf1, qf, C[1], 0,0,0);

            // exp2 in place, lane-local tree sum, cross-half shfl_xor, rcp
            float t[8];
            #pragma unroll
            for (int jt = 0; jt < 2; ++jt)
                #pragma unroll
                for (int g = 0; g < 4; ++g) {
                    const int b = g*4;
                    C[jt][b+0] = __builtin_amdgcn_exp2f(C[jt][b+0]);
                    C[jt][b+1] = __builtin_amdgcn_exp2f(C[jt][b+1]);
                    C[jt][b+2] = __builtin_amdgcn_exp2f(C[jt][b+2]);
                    C[jt][b+3] = __builtin_amdgcn_exp2f(C[jt][b+3]);
                    t[jt*4+g] = (C[jt][b+0]+C[jt][b+1]) + (C[jt][b+2]+C[jt][b+3]);
                }
            const float sum = ((t[0]+t[1])+(t[2]+t[3])) + ((t[4]+t[5])+(t[6]+t[7]));
            const float tot = sum + __shfl_xor(sum, 32, 64);
            const float iv  = __builtin_amdgcn_rcpf(tot);

            // PV: A-frags in-register (cvt_pk of normalized P + permlane32_swap)
            f32x16 O = {};
            #pragma unroll
            for (int kt = 0; kt < 4; ++kt) {
                const int jt = kt >> 1;
                const int q8 = (kt & 1) * 8;
                unsigned int A0 = cvt_pk_bf16(C[jt][q8+0]*iv, C[jt][q8+1]*iv);
                unsigned int A1 = cvt_pk_bf16(C[jt][q8+2]*iv, C[jt][q8+3]*iv);
                unsigned int B0 = cvt_pk_bf16(C[jt][q8+4]*iv, C[jt][q8+5]*iv);
                unsigned int B1 = cvt_pk_bf16(C[jt][q8+6]*iv, C[jt][q8+7]*iv);
                permswap(A0, B0);
                permswap(A1, B1);
                union { unsigned int u[4]; bf16x8 v; } af;
                af.u[0] = A0; af.u[1] = A1; af.u[2] = B0; af.u[3] = B1;
                O = __builtin_amdgcn_mfma_f32_32x32x16_bf16(af.v, vb[kt], O, 0,0,0);
            }

            // store: lane holds col c=cB (<8), rows i = (r&3)+8(r>>2)+4*hiB
            if (cB < 8) {
                float* ob = out + (size_t)w*4096 + (size_t)(it*32)*64 + h*8 + cB;
                #pragma unroll
                for (int r = 0; r < 16; ++r) {
                    const int iloc = (r&3) + 8*(r>>2) + 4*hiB;
                    ob[(size_t)iloc*64] = O[r];
                }
            }
        }
    }
}

extern "C" void kernel_launch(void* const* d_in, const int* in_sizes, int n_in,
                              void* d_out, int out_size, void* d_ws, size_t ws_size,
                              hipStream_t stream)
{
    const float* x   = (const float*)d_in[0];
    const float* Wq  = (const float*)d_in[1];
    const float* bq  = (const float*)d_in[2];
    const float* pos = (const float*)d_in[3];
    float* out = (float*)d_out;
    float* pp  = (float*)d_ws;   // 128 KB

    hipLaunchKernelGGL(prep_pos, dim3(128), dim3(256), 0, stream, pos, pp);
    hipLaunchKernelGGL(lm_mfma, dim3(8192), dim3(256), 0, stream, x, Wq, bq, pp, out);
}

// Round 11
// 134.138 us; speedup vs baseline: 1.0687x; 1.0212x over previous
//
#include <hip/hip_runtime.h>
#include <math.h>

// local_mixer via bf16 MFMA. R11: S^T-swapped QK^T (32x32, in-register
// softmax w/ lane-local rowsum) + P staged to LDS via pair-packed b64 stores
// (rotation+XOR swizzle, conflict-free W&R) + PV as 16x16x32 (2 independent
// accumulator chains, half the MFMA-pipe waste of 32x32 PV). Two-pass QKV
// (reg-lean), sVT aliases dead sX. No explicit waitcnt, no setprio.
//   x:[8,256,256,64]f32  W:[192,64]f32  b:[192]f32  pos:[1,8,64,64]f32
//   out:[8192,64,64]f32

typedef __attribute__((ext_vector_type(8)))  short bf16x8;
typedef __attribute__((ext_vector_type(4)))  float f32x4;
typedef __attribute__((ext_vector_type(16))) float f32x16;

__device__ inline unsigned int cvt_pk_bf16(float lo, float hi) {
    unsigned int r;
    asm("v_cvt_pk_bf16_f32 %0, %1, %2" : "=v"(r) : "v"(lo), "v"(hi));
    return r;
}
__device__ inline bf16x8 pack8(float4 a, float4 b) {
    union { unsigned int u[4]; bf16x8 v; } r;
    r.u[0] = cvt_pk_bf16(a.x, a.y);
    r.u[1] = cvt_pk_bf16(a.z, a.w);
    r.u[2] = cvt_pk_bf16(b.x, b.y);
    r.u[3] = cvt_pk_bf16(b.z, b.w);
    return r.v;
}

// ---- prep: pos -> f32 S^T-C-layout fragments, *log2e, into d_ws (128 KB) ----
// flat = (((h*2 + it)*2 + jt)*64 + lane)*16 + reg
__global__ __launch_bounds__(256) void prep_pos(const float* __restrict__ pos,
                                                float* __restrict__ pp)
{
    int flat = blockIdx.x * 256 + threadIdx.x;   // 0..32767
    int r  = flat & 15;
    int ln = (flat >> 4) & 63;
    int jt = (flat >> 10) & 1;
    int it = (flat >> 11) & 1;
    int h  = flat >> 12;
    int j = jt*32 + (r & 3) + 8*(r >> 2) + 4*(ln >> 5);   // S^T row
    int i = it*32 + (ln & 31);                            // S^T col
    pp[flat] = pos[(h*64 + i)*64 + j] * 1.4426950408889634f;
}

__global__ __launch_bounds__(256, 4) void lm_mfma(const float* __restrict__ x,
                                                  const float* __restrict__ Wq,
                                                  const float* __restrict__ bq,
                                                  const float* __restrict__ ppf,
                                                  float* __restrict__ out)
{
    // 40 KB LDS (4 blocks/CU).
    // sXV/sQ/sK: chunk-swizzle (8-bf16 chunk c8 of row r at c8^(r&7)).
    // sP: per-wave [32][64] bf16; chunk ch = ((lc ^ (i&7)) + 2*(i>>3)) & 7
    //     -> conflict-free uint2 writes AND b128 reads (derived, verified).
    __shared__ unsigned short sXV[64*64];   // x [n][c] during QKV; v^T [c][j] in attn
    __shared__ unsigned short sQ [64*64];   // q (scaled*log2e) [i][d]
    __shared__ unsigned short sK [64*64];   // k [j][d]
    __shared__ unsigned short sP [4*32*64]; // per-wave P tile [i][j]

    const int tid = threadIdx.x;
    const int w   = blockIdx.x;
    const int ln  = tid & 63;
    const int wv  = tid >> 6;
    const int lr  = ln & 15;
    const int lg  = ln >> 4;

    const int bi = w >> 10, mm = w & 1023;
    const int mh = mm >> 5, mw = mm & 31;
    const float* xwin = x + ((size_t)(bi*256 + mh*8)*256 + mw*8)*64;

    // ---- stage x -> sXV (bf16, swizzled) ----
    #pragma unroll
    for (int r = 0; r < 4; ++r) {
        const int f4 = tid + r*256;
        const int n  = f4 >> 4;
        const int c  = (f4 & 15) * 4;
        const float4 v = *(const float4*)(xwin + ((size_t)(n>>3)*256 + (n&7))*64 + c);
        uint2 u;
        u.x = cvt_pk_bf16(v.x, v.y);
        u.y = cvt_pk_bf16(v.z, v.w);
        *(uint2*)&sXV[n*64 + (((c>>3) ^ (n&7))<<3) + (c&7)] = u;
    }

    const float qs = 0.35355339059327373f * 1.4426950408889634f;  // 8^-0.5 * log2e

    __syncthreads();

    // ---- QKV pass A: Q and K (wave wv owns d-tiles wv (Q), wv+4 (K)) ----
    {
        bf16x8 wfQ[2], wfK[2];
        #pragma unroll
        for (int kt = 0; kt < 2; ++kt) {
            const float* bz = Wq + (size_t)(wv*16 + lr)*64 + kt*32 + lg*8;
            wfQ[kt] = pack8(*(const float4*)bz, *(const float4*)(bz+4));
            bz += (size_t)64*64;
            wfK[kt] = pack8(*(const float4*)bz, *(const float4*)(bz+4));
        }
        const float4 bqQr = *(const float4*)(bq      + wv*16 + lg*4);
        const float4 bqK  = *(const float4*)(bq + 64 + wv*16 + lg*4);
        float4 bqQs;
        bqQs.x = bqQr.x*qs; bqQs.y = bqQr.y*qs; bqQs.z = bqQr.z*qs; bqQs.w = bqQr.w*qs;

        f32x4 aQ[4], aK[4];
        #pragma unroll
        for (int nt = 0; nt < 4; ++nt) { aQ[nt]=0; aK[nt]=0; }
        #pragma unroll
        for (int nt = 0; nt < 4; ++nt) {
            #pragma unroll
            for (int kt = 0; kt < 2; ++kt) {
                const int n  = lr + nt*16;
                const int c8 = lg + kt*4;
                const bf16x8 xf = *(const bf16x8*)&sXV[n*64 + ((c8 ^ (n&7))<<3)];
                aQ[nt] = __builtin_amdgcn_mfma_f32_16x16x32_bf16(wfQ[kt], xf, aQ[nt], 0,0,0);
                aK[nt] = __builtin_amdgcn_mfma_f32_16x16x32_bf16(wfK[kt], xf, aK[nt], 0,0,0);
            }
        }
        #pragma unroll
        for (int nt = 0; nt < 4; ++nt) {
            const int n  = lr + nt*16;
            const int d0 = wv*16 + lg*4;
            const int qidx = n*64 + (((d0>>3) ^ (n&7))<<3) + (d0&7);
            uint2 uq, uk;
            uq.x = cvt_pk_bf16(fmaf(aQ[nt][0], qs, bqQs.x), fmaf(aQ[nt][1], qs, bqQs.y));
            uq.y = cvt_pk_bf16(fmaf(aQ[nt][2], qs, bqQs.z), fmaf(aQ[nt][3], qs, bqQs.w));
            uk.x = cvt_pk_bf16(aK[nt][0]+bqK.x, aK[nt][1]+bqK.y);
            uk.y = cvt_pk_bf16(aK[nt][2]+bqK.z, aK[nt][3]+bqK.w);
            *(uint2*)&sQ[qidx] = uq;
            *(uint2*)&sK[qidx] = uk;
        }
    }

    // ---- QKV pass B: V into AGPRs (write deferred until sX is dead) ----
    f32x4 aV[4];
    {
        bf16x8 wfV[2];
        #pragma unroll
        for (int kt = 0; kt < 2; ++kt) {
            const float* bz = Wq + (size_t)(128 + wv*16 + lr)*64 + kt*32 + lg*8;
            wfV[kt] = pack8(*(const float4*)bz, *(const float4*)(bz+4));
        }
        #pragma unroll
        for (int nt = 0; nt < 4; ++nt) aV[nt] = 0;
        #pragma unroll
        for (int nt = 0; nt < 4; ++nt) {
            #pragma unroll
            for (int kt = 0; kt < 2; ++kt) {
                const int n  = lr + nt*16;
                const int c8 = lg + kt*4;
                const bf16x8 xf = *(const bf16x8*)&sXV[n*64 + ((c8 ^ (n&7))<<3)];
                aV[nt] = __builtin_amdgcn_mfma_f32_16x16x32_bf16(xf, wfV[kt], aV[nt], 0,0,0);
            }
        }
    }

    __syncthreads();   // everyone done reading sX

    {
        const float bqV = bq[128 + wv*16 + lr];
        #pragma unroll
        for (int nt = 0; nt < 4; ++nt) {
            const int cc = wv*16 + lr;
            const int n0 = nt*16 + lg*4;
            uint2 uv;
            uv.x = cvt_pk_bf16(aV[nt][0]+bqV, aV[nt][1]+bqV);
            uv.y = cvt_pk_bf16(aV[nt][2]+bqV, aV[nt][3]+bqV);
            *(uint2*)&sXV[cc*64 + (((n0>>3) ^ (cc&7))<<3) + (n0&7)] = uv;  // v^T over sX
        }
    }

    __syncthreads();   // sVT visible

    // ---- attention: wave wv -> heads {2wv, 2wv+1} x i-tiles {0,1}, unit-serial ----
    unsigned short* const pw = sP + wv*2048;   // this wave's P tile [32][64]
    const int iloc = ln & 31;
    const int hi4  = (ln >> 5) * 4;

    #pragma unroll 1
    for (int hh = 0; hh < 2; ++hh) {
        const int h = wv*2 + hh;

        // PV B-frags (16x16x32): lane col = lr (<8 = head channel, else zero);
        // k = j = kt*32 + lg*8 + e, read from sVT rows cc = h*8+lr.
        bf16x8 vb[2];
        #pragma unroll
        for (int kt = 0; kt < 2; ++kt) {
            bf16x8 z = {};
            vb[kt] = z;
            if (lr < 8) {
                const int cc = h*8 + lr;
                vb[kt] = *(const bf16x8*)&sXV[cc*64 + ((((kt*4+lg) ^ (cc&7)))<<3)];
            }
        }

        #pragma unroll 1
        for (int it = 0; it < 2; ++it) {
            // C-init = pos fragments (f32, *log2e, pre-permuted): pure loads
            f32x16 C[2];
            #pragma unroll
            for (int jt = 0; jt < 2; ++jt)
                C[jt] = *(const f32x16*)(ppf + ((((h*2+it)*2 + jt)*64) + ln)*16);

            // swapped QK^T: S^T tiles = K · Q^T (32x32x16, K=8 of 16; hi lanes zero)
            bf16x8 qf = {}, kf0 = {}, kf1 = {};
            if (ln < 32) {
                const int i = it*32 + ln;
                qf  = *(const bf16x8*)&sQ[i*64 + ((h ^ (i&7))<<3)];
                kf0 = *(const bf16x8*)&sK[ln*64 + ((h ^ (ln&7))<<3)];
                const int j1 = 32 + ln;
                kf1 = *(const bf16x8*)&sK[j1*64 + ((h ^ (j1&7))<<3)];
            }
            C[0] = __builtin_amdgcn_mfma_f32_32x32x16_bf16(kf0, qf, C[0], 0,0,0);
            C[1] = __builtin_amdgcn_mfma_f32_32x32x16_bf16(kf1, qf, C[1], 0,0,0);

            // exp2 in place, lane-local tree sum, cross-half shfl_xor, rcp
            float t[8];
            #pragma unroll
            for (int jt = 0; jt < 2; ++jt)
                #pragma unroll
                for (int g = 0; g < 4; ++g) {
                    const int b = g*4;
                    C[jt][b+0] = __builtin_amdgcn_exp2f(C[jt][b+0]);
                    C[jt][b+1] = __builtin_amdgcn_exp2f(C[jt][b+1]);
                    C[jt][b+2] = __builtin_amdgcn_exp2f(C[jt][b+2]);
                    C[jt][b+3] = __builtin_amdgcn_exp2f(C[jt][b+3]);
                    t[jt*4+g] = (C[jt][b+0]+C[jt][b+1]) + (C[jt][b+2]+C[jt][b+3]);
                }
            const float sum = ((t[0]+t[1])+(t[2]+t[3])) + ((t[4]+t[5])+(t[6]+t[7]));
            const float tot = sum + __shfl_xor(sum, 32, 64);
            const float iv  = __builtin_amdgcn_rcpf(tot);

            // pack normalized P pairs (j-contiguous in S^T layout) -> sP.
            // store: row iloc, logical chunk lc = jt*4+G (j = lc*8 + 4*hi + 0..3)
            #pragma unroll
            for (int jt = 0; jt < 2; ++jt)
                #pragma unroll
                for (int G = 0; G < 4; ++G) {
                    uint2 u;
                    u.x = cvt_pk_bf16(C[jt][4*G+0]*iv, C[jt][4*G+1]*iv);
                    u.y = cvt_pk_bf16(C[jt][4*G+2]*iv, C[jt][4*G+3]*iv);
                    const int lc = jt*4 + G;
                    const int ch = ((lc ^ (iloc&7)) + 2*(iloc>>3)) & 7;
                    *(uint2*)&pw[iloc*64 + ch*8 + hi4] = u;
                }

            // PV: 16x16x32, A = P rows from sP (b128, conflict-free), B = vb.
            // Two independent accumulator chains (pit).
            f32x4 O[2]; O[0] = 0; O[1] = 0;
            #pragma unroll
            for (int pit = 0; pit < 2; ++pit)
                #pragma unroll
                for (int kt = 0; kt < 2; ++kt) {
                    const int row = pit*16 + lr;
                    const int lc  = kt*4 + lg;
                    const int ch  = ((lc ^ (row&7)) + 2*(row>>3)) & 7;
                    const bf16x8 pf = *(const bf16x8*)&pw[row*64 + ch*8];
                    O[pit] = __builtin_amdgcn_mfma_f32_16x16x32_bf16(pf, vb[kt], O[pit], 0,0,0);
                }

            // store: lane col c = lr (<8), rows i = it*32 + pit*16 + lg*4 + r
            if (lr < 8) {
                #pragma unroll
                for (int pit = 0; pit < 2; ++pit) {
                    float* ob = out + (size_t)w*4096
                              + (size_t)(it*32 + pit*16 + lg*4)*64 + h*8 + lr;
                    ob[0]   = O[pit][0];
                    ob[64]  = O[pit][1];
                    ob[128] = O[pit][2];
                    ob[192] = O[pit][3];
                }
            }
        }
    }
}

extern "C" void kernel_launch(void* const* d_in, const int* in_sizes, int n_in,
                              void* d_out, int out_size, void* d_ws, size_t ws_size,
                              hipStream_t stream)
{
    const float* x   = (const float*)d_in[0];
    const float* Wq  = (const float*)d_in[1];
    const float* bq  = (const float*)d_in[2];
    const float* pos = (const float*)d_in[3];
    float* out = (float*)d_out;
    float* pp  = (float*)d_ws;   // 128 KB

    hipLaunchKernelGGL(prep_pos, dim3(128), dim3(256), 0, stream, pos, pp);
    hipLaunchKernelGGL(lm_mfma, dim3(8192), dim3(256), 0, stream, x, Wq, bq, pp, out);
}

// Round 12
// 98.772 us; speedup vs baseline: 1.4514x; 1.3581x over previous
//
#include <hip/hip_runtime.h>
#include <math.h>

// local_mixer via bf16 MFMA. R12 = R4 (126us champion) + it-pair software
// pipelining: both i-tile units' C-init/frag loads and QK MFMAs issue up
// front (kf shared); exp/pack/PV of the two units interleave in one
// scheduling region. Explicit lgkmcnt(0) full-stop removed -- per-wave DS
// FIFO ordering + compiler counted waits handle pack->PV (RAW) and
// unit1-pack vs unit0-PV (WAR on the shared per-wave sP).
//   x:[8,256,256,64]f32  W:[192,64]f32  b:[192]f32  pos:[1,8,64,64]f32
//   out:[8192,64,64]f32

typedef __attribute__((ext_vector_type(8)))  short bf16x8;
typedef __attribute__((ext_vector_type(4)))  float f32x4;
typedef __attribute__((ext_vector_type(16))) float f32x16;

__device__ inline unsigned int cvt_pk_bf16(float lo, float hi) {
    unsigned int r;
    asm("v_cvt_pk_bf16_f32 %0, %1, %2" : "=v"(r) : "v"(lo), "v"(hi));
    return r;
}
__device__ inline unsigned short f2bf(float f) {   // prep kernel only
    unsigned int u = __builtin_bit_cast(unsigned int, f);
    return (unsigned short)((u + 0x7FFFu + ((u >> 16) & 1u)) >> 16);
}
#define BFLO(u) __builtin_bit_cast(float, (unsigned int)((u) << 16))
#define BFHI(u) __builtin_bit_cast(float, (unsigned int)((u) & 0xffff0000u))

__device__ inline bf16x8 pack8(float4 a, float4 b) {
    union { unsigned int u[4]; bf16x8 v; } r;
    r.u[0] = cvt_pk_bf16(a.x, a.y);
    r.u[1] = cvt_pk_bf16(a.z, a.w);
    r.u[2] = cvt_pk_bf16(b.x, b.y);
    r.u[3] = cvt_pk_bf16(b.z, b.w);
    return r.v;
}

// ---- prep: pos^T fragments (32x32 C layout of S^T tiles), *log2e, bf16 ----
// flat = (((h*2 + it)*2 + jt)*64 + lane)*16 + reg
__global__ __launch_bounds__(256) void prep_pos(const float* __restrict__ pos,
                                                unsigned short* __restrict__ pp)
{
    int flat = blockIdx.x * 256 + threadIdx.x;   // 0..32767
    int r  = flat & 15;
    int ln = (flat >> 4) & 63;
    int jt = (flat >> 10) & 1;
    int it = (flat >> 11) & 1;
    int h  = flat >> 12;
    int j = jt*32 + (r & 3) + 8*(r >> 2) + 4*(ln >> 5);   // S^T row
    int i = it*32 + (ln & 31);                            // S^T col
    pp[flat] = f2bf(pos[(h*64 + i)*64 + j] * 1.4426950408889634f);
}

__global__ __launch_bounds__(256, 3) void lm_mfma(const float* __restrict__ x,
                                                  const float* __restrict__ Wq,
                                                  const float* __restrict__ bq,
                                                  const unsigned short* __restrict__ pp,
                                                  float* __restrict__ out)
{
    // 40 KB LDS. Chunk-swizzle: 8-bf16 chunk c8 of row r at c8^(r&7).
    __shared__ unsigned short sPool[4*32*64];  // 16 KB: sX (8 KB) then sP (16 KB)
    __shared__ unsigned short sQ [64*64];      // q (scaled*log2e) [i][d]
    __shared__ unsigned short sK [64*64];      // k [j][d]
    __shared__ unsigned short sVT[64*64];      // v^T [c][j]
    unsigned short* const sX = sPool;
    unsigned short* const sP = sPool;

    const int tid = threadIdx.x;
    const int w   = blockIdx.x;
    const int ln  = tid & 63;
    const int wv  = tid >> 6;
    const int lr  = ln & 15;
    const int lg  = ln >> 4;

    const int bi = w >> 10, mm = w & 1023;
    const int mh = mm >> 5, mw = mm & 31;
    const float* xwin = x + ((size_t)(bi*256 + mh*8)*256 + mw*8)*64;

    // ---- stage x -> sX (bf16, swizzled) ----
    #pragma unroll
    for (int r = 0; r < 4; ++r) {
        const int f4 = tid + r*256;
        const int n  = f4 >> 4;
        const int c  = (f4 & 15) * 4;
        const float4 v = *(const float4*)(xwin + ((size_t)(n>>3)*256 + (n&7))*64 + c);
        uint2 u;
        u.x = cvt_pk_bf16(v.x, v.y);
        u.y = cvt_pk_bf16(v.z, v.w);
        *(uint2*)&sX[n*64 + (((c>>3) ^ (n&7))<<3) + (c&7)] = u;
    }

    // ---- W fragments: wave wv owns d-tiles {wv, wv+4, wv+8} ----
    bf16x8 wfrag[3][2];
    #pragma unroll
    for (int t = 0; t < 3; ++t) {
        const int d = (wv + 4*t)*16 + lr;
        #pragma unroll
        for (int kt = 0; kt < 2; ++kt) {
            const float* base = Wq + (size_t)d*64 + kt*32 + lg*8;
            wfrag[t][kt] = pack8(*(const float4*)base, *(const float4*)(base+4));
        }
    }
    const float qs = 0.35355339059327373f * 1.4426950408889634f;  // 8^-0.5 * log2e
    const float4 bqQr = *(const float4*)(bq       + wv*16 + lg*4);
    const float4 bqK  = *(const float4*)(bq + 64  + wv*16 + lg*4);
    const float  bqV  = bq[128 + wv*16 + lr];
    float4 bqQs;
    bqQs.x = bqQr.x*qs; bqQs.y = bqQr.y*qs; bqQs.z = bqQr.z*qs; bqQs.w = bqQr.w*qs;

    __syncthreads();

    // ---- QKV MFMAs (16x16x32, single pass) ----
    f32x4 aQ[4], aK[4], aV[4];
    #pragma unroll
    for (int nt = 0; nt < 4; ++nt) { aQ[nt]=0; aK[nt]=0; aV[nt]=0; }

    #pragma unroll
    for (int nt = 0; nt < 4; ++nt) {
        #pragma unroll
        for (int kt = 0; kt < 2; ++kt) {
            const int n  = lr + nt*16;
            const int c8 = lg + kt*4;
            const bf16x8 xf = *(const bf16x8*)&sX[n*64 + ((c8 ^ (n&7))<<3)];
            aQ[nt] = __builtin_amdgcn_mfma_f32_16x16x32_bf16(wfrag[0][kt], xf, aQ[nt], 0,0,0);
            aK[nt] = __builtin_amdgcn_mfma_f32_16x16x32_bf16(wfrag[1][kt], xf, aK[nt], 0,0,0);
            aV[nt] = __builtin_amdgcn_mfma_f32_16x16x32_bf16(xf, wfrag[2][kt], aV[nt], 0,0,0);
        }
    }

    #pragma unroll
    for (int nt = 0; nt < 4; ++nt) {
        const int n  = lr + nt*16;
        const int d0 = wv*16 + lg*4;
        const int qidx = n*64 + (((d0>>3) ^ (n&7))<<3) + (d0&7);
        uint2 uq, uk;
        uq.x = cvt_pk_bf16(fmaf(aQ[nt][0], qs, bqQs.x), fmaf(aQ[nt][1], qs, bqQs.y));
        uq.y = cvt_pk_bf16(fmaf(aQ[nt][2], qs, bqQs.z), fmaf(aQ[nt][3], qs, bqQs.w));
        uk.x = cvt_pk_bf16(aK[nt][0]+bqK.x, aK[nt][1]+bqK.y);
        uk.y = cvt_pk_bf16(aK[nt][2]+bqK.z, aK[nt][3]+bqK.w);
        *(uint2*)&sQ[qidx] = uq;
        *(uint2*)&sK[qidx] = uk;
        const int cc = wv*16 + lr;
        const int n0 = nt*16 + lg*4;
        uint2 uv;
        uv.x = cvt_pk_bf16(aV[nt][0]+bqV, aV[nt][1]+bqV);
        uv.y = cvt_pk_bf16(aV[nt][2]+bqV, aV[nt][3]+bqV);
        *(uint2*)&sVT[cc*64 + (((n0>>3) ^ (cc&7))<<3) + (n0&7)] = uv;
    }

    __syncthreads();

    // ---- attention: wave wv -> heads {2wv, 2wv+1}; it-pair pipelined ----
    unsigned short* const pw = sP + ((wv*32 + (ln & 31)) << 6);  // this lane's P row
    const int il  = ln & 31;
    const int hi4 = (ln >> 5) * 4;

    #pragma unroll 1
    for (int hh = 0; hh < 2; ++hh) {
        const int h = wv*2 + hh;

        // V^T B-frags for 16x16 PV (cols 8..15 zero), shared by both i-tiles
        bf16x8 vf[2];
        #pragma unroll
        for (int kt = 0; kt < 2; ++kt) {
            bf16x8 z = {};
            vf[kt] = z;
            if (lr < 8) {
                const int cc = h*8 + lr;
                const int j0 = kt*32 + lg*8;
                vf[kt] = *(const bf16x8*)&sVT[cc*64 + (((j0>>3) ^ (cc&7))<<3)];
            }
        }

        // C-init = pos^T fragments (bf16, *log2e, pre-permuted), both i-tiles
        f32x16 C[2][2];
        #pragma unroll
        for (int it = 0; it < 2; ++it)
            #pragma unroll
            for (int jt = 0; jt < 2; ++jt) {
                const unsigned short* pb = pp + (((h*2+it)*2 + jt)*64 + ln)*16;
                const uint4 a = *(const uint4*)(pb);
                const uint4 b = *(const uint4*)(pb + 8);
                C[it][jt][0]=BFLO(a.x);  C[it][jt][1]=BFHI(a.x);
                C[it][jt][2]=BFLO(a.y);  C[it][jt][3]=BFHI(a.y);
                C[it][jt][4]=BFLO(a.z);  C[it][jt][5]=BFHI(a.z);
                C[it][jt][6]=BFLO(a.w);  C[it][jt][7]=BFHI(a.w);
                C[it][jt][8]=BFLO(b.x);  C[it][jt][9]=BFHI(b.x);
                C[it][jt][10]=BFLO(b.y); C[it][jt][11]=BFHI(b.y);
                C[it][jt][12]=BFLO(b.z); C[it][jt][13]=BFHI(b.z);
                C[it][jt][14]=BFLO(b.w); C[it][jt][15]=BFHI(b.w);
            }

        // swapped QK^T: S^T = K·Q^T (32x32x16, K=8 of 16). kf shared by both i-tiles.
        bf16x8 qf0 = {}, qf1 = {}, kf0 = {}, kf1 = {};
        if (ln < 32) {
            qf0 = *(const bf16x8*)&sQ[ln*64 + ((h ^ (ln&7))<<3)];
            const int i1 = 32 + ln;
            qf1 = *(const bf16x8*)&sQ[i1*64 + ((h ^ (i1&7))<<3)];
            kf0 = *(const bf16x8*)&sK[ln*64 + ((h ^ (ln&7))<<3)];
            kf1 = *(const bf16x8*)&sK[i1*64 + ((h ^ (i1&7))<<3)];
        }
        C[0][0] = __builtin_amdgcn_mfma_f32_32x32x16_bf16(kf0, qf0, C[0][0], 0,0,0);
        C[0][1] = __builtin_amdgcn_mfma_f32_32x32x16_bf16(kf1, qf0, C[0][1], 0,0,0);
        C[1][0] = __builtin_amdgcn_mfma_f32_32x32x16_bf16(kf0, qf1, C[1][0], 0,0,0);
        C[1][1] = __builtin_amdgcn_mfma_f32_32x32x16_bf16(kf1, qf1, C[1][1], 0,0,0);

        // per i-tile: exp2 -> lane-local sum -> normalized pack -> sP -> PV.
        // Fully unrolled pair: unit 1's VALU overlaps unit 0's DS/MFMA.
        // No explicit lgkm drain: per-wave DS FIFO orders pack/read; compiler
        // inserts counted waits for the data deps.
        f32x4 O[2][2];
        #pragma unroll
        for (int it = 0; it < 2; ++it) {
            float t[8];
            #pragma unroll
            for (int jt = 0; jt < 2; ++jt)
                #pragma unroll
                for (int g = 0; g < 4; ++g) {
                    const int b = g*4;
                    C[it][jt][b+0] = __builtin_amdgcn_exp2f(C[it][jt][b+0]);
                    C[it][jt][b+1] = __builtin_amdgcn_exp2f(C[it][jt][b+1]);
                    C[it][jt][b+2] = __builtin_amdgcn_exp2f(C[it][jt][b+2]);
                    C[it][jt][b+3] = __builtin_amdgcn_exp2f(C[it][jt][b+3]);
                    t[jt*4+g] = (C[it][jt][b+0]+C[it][jt][b+1])
                              + (C[it][jt][b+2]+C[it][jt][b+3]);
                }
            const float sum = ((t[0]+t[1])+(t[2]+t[3])) + ((t[4]+t[5])+(t[6]+t[7]));
            const float tot = sum + __shfl_xor(sum, 32, 64);
            const float iv  = __builtin_amdgcn_rcpf(tot);

            // pack normalized P pairs -> this lane's sP row (R4 swizzle)
            #pragma unroll
            for (int jt = 0; jt < 2; ++jt)
                #pragma unroll
                for (int G = 0; G < 4; ++G) {
                    uint2 u;
                    u.x = cvt_pk_bf16(C[it][jt][4*G+0]*iv, C[it][jt][4*G+1]*iv);
                    u.y = cvt_pk_bf16(C[it][jt][4*G+2]*iv, C[it][jt][4*G+3]*iv);
                    const int j0 = jt*32 + 8*G + hi4;
                    *(uint2*)&pw[(((j0>>3) ^ (il&7))<<3) + (j0&7)] = u;
                }

            // PV: 16x16x32, A = P rows (b128), B = vf. Two independent chains.
            O[it][0] = 0; O[it][1] = 0;
            #pragma unroll
            for (int pit = 0; pit < 2; ++pit)
                #pragma unroll
                for (int kt = 0; kt < 2; ++kt) {
                    const int i = pit*16 + lr;
                    const bf16x8 pf = *(const bf16x8*)&sP[(wv*32+i)*64
                                      + (((kt*4+lg) ^ (i&7))<<3)];
                    O[it][pit] = __builtin_amdgcn_mfma_f32_16x16x32_bf16(pf, vf[kt],
                                                                         O[it][pit], 0,0,0);
                }
        }

        // stores: lane col c = lr (<8), rows i = it*32 + pit*16 + lg*4 + r
        if (lr < 8) {
            #pragma unroll
            for (int it = 0; it < 2; ++it)
                #pragma unroll
                for (int pit = 0; pit < 2; ++pit) {
                    float* ob = out + (size_t)w*4096
                              + (size_t)(it*32 + pit*16 + lg*4)*64 + h*8 + lr;
                    ob[0]   = O[it][pit][0];
                    ob[64]  = O[it][pit][1];
                    ob[128] = O[it][pit][2];
                    ob[192] = O[it][pit][3];
                }
        }
    }
}

extern "C" void kernel_launch(void* const* d_in, const int* in_sizes, int n_in,
                              void* d_out, int out_size, void* d_ws, size_t ws_size,
                              hipStream_t stream)
{
    const float* x   = (const float*)d_in[0];
    const float* Wq  = (const float*)d_in[1];
    const float* bq  = (const float*)d_in[2];
    const float* pos = (const float*)d_in[3];
    float* out = (float*)d_out;
    unsigned short* pp = (unsigned short*)d_ws;   // 64 KB

    hipLaunchKernelGGL(prep_pos, dim3(128), dim3(256), 0, stream, pos, pp);
    hipLaunchKernelGGL(lm_mfma, dim3(8192), dim3(256), 0, stream, x, Wq, bq, pp, out);
}